// Round 1
// baseline (2249.304 us; speedup 1.0000x reference)
//
#include <hip/hip_runtime.h>

// Problem constants (B=8, T=2048 -> NTOK=16384; D=1024, E=8, F=4096, top_k=2)
#define NTOK 16384
#define DDIM 1024
#define FDIM 4096
#define NEXP 8
#define PAIRS (NTOK * 2)
#define PADPAIRS 33792          // 264 * 128 (worst-case 128-padded segments)
#define MAXTILES 264
#define CHUNK_TILES 66
#define NCHUNKS 4
#define CHUNK_ROWS (CHUNK_TILES * 128)

// Workspace layout (bytes)
#define WS_XB      0ull                    // bf16 x       [NTOK][D]      33,554,432
#define WS_WFCB    33554432ull             // bf16 wfc     [E][F][D]      67,108,864
#define WS_WPROJB  100663296ull            // bf16 wproj   [E][D][F]      67,108,864
#define WS_H       167772160ull            // bf16 h       [CHUNK_ROWS][F] 69,206,016
#define WS_PTOK    236978176ull            // int  pair_token [PADPAIRS]
#define WS_PGATE   237113344ull            // f32  pair_gate  [PADPAIRS]
#define WS_TIDX    237248512ull            // int  tok_idx  [NTOK][2]
#define WS_TGATE   237379584ull            // f32  tok_gate [NTOK][2]
#define WS_META    237510656ull            // ints: counts[8] cursor[8] seg[8] total[1] pad, tile2e[264]

typedef short bf16x8 __attribute__((ext_vector_type(8)));
typedef float f32x4 __attribute__((ext_vector_type(4)));

__device__ __forceinline__ unsigned short f2bf(float f) {
    unsigned int u = __float_as_uint(f);
    u += 0x7fffu + ((u >> 16) & 1u);   // round to nearest even
    return (unsigned short)(u >> 16);
}

// ---------------- fp32 -> bf16 weight conversion ----------------
__global__ __launch_bounds__(256) void convert_kernel(const float* __restrict__ src,
                                                      unsigned short* __restrict__ dst) {
    int i = blockIdx.x * 256 + threadIdx.x;     // one float4 per thread
    float4 v = ((const float4*)src)[i];
    ushort4 o;
    o.x = f2bf(v.x); o.y = f2bf(v.y); o.z = f2bf(v.z); o.w = f2bf(v.w);
    ((ushort4*)dst)[i] = o;
}

// ---------------- router: logits (fp32), top-2 + softmax gates, x->bf16 ----------------
__global__ __launch_bounds__(256) void router_kernel(const float* __restrict__ x,
                                                     const float* __restrict__ rw,
                                                     unsigned short* __restrict__ xb,
                                                     float* __restrict__ logits,
                                                     int* __restrict__ tok_idx,
                                                     float* __restrict__ tok_gate,
                                                     int* __restrict__ counts) {
    __shared__ float srw[NEXP * DDIM];          // 32 KiB
    int tid = threadIdx.x;
    for (int i = tid; i < NEXP * DDIM; i += 256) srw[i] = rw[i];
    __syncthreads();

    int wave = tid >> 6, lane = tid & 63;
    int t = blockIdx.x * 4 + wave;              // one token per wave
    const float* xr = x + (size_t)t * DDIM;
    unsigned short* xbr = xb + (size_t)t * DDIM;

    float acc[NEXP];
#pragma unroll
    for (int e = 0; e < NEXP; e++) acc[e] = 0.f;

    for (int i = 0; i < DDIM / 64; i++) {
        int k = lane + i * 64;
        float xv = xr[k];
        xbr[k] = f2bf(xv);
#pragma unroll
        for (int e = 0; e < NEXP; e++) acc[e] += xv * srw[e * DDIM + k];
    }
#pragma unroll
    for (int off = 32; off > 0; off >>= 1) {
#pragma unroll
        for (int e = 0; e < NEXP; e++) acc[e] += __shfl_down(acc[e], off);
    }
    if (lane == 0) {
        float v0 = -1e30f, v1 = -1e30f; int i0 = 0, i1 = 0;
#pragma unroll
        for (int e = 0; e < NEXP; e++) {
            float v = acc[e];
            logits[(size_t)t * NEXP + e] = v;
            if (v > v0)      { v1 = v0; i1 = i0; v0 = v; i0 = e; }
            else if (v > v1) { v1 = v;  i1 = e; }
        }
        float d = __expf(v1 - v0);              // <= 1, stable
        float g0 = 1.f / (1.f + d);
        float g1 = d * g0;
        tok_idx[t * 2 + 0] = i0; tok_idx[t * 2 + 1] = i1;
        tok_gate[t * 2 + 0] = g0; tok_gate[t * 2 + 1] = g1;
        atomicAdd(&counts[i0], 1);
        atomicAdd(&counts[i1], 1);
    }
}

// ---------------- segment planning + pair-array padding init ----------------
__global__ void seg_plan(const int* __restrict__ counts, int* __restrict__ seg_start,
                         int* __restrict__ tile2e, int* __restrict__ total_tiles,
                         int* __restrict__ pair_token, float* __restrict__ pair_gate) {
    if (threadIdx.x == 0) {
        int cum = 0, tl = 0;
        for (int e = 0; e < NEXP; e++) {
            seg_start[e] = cum;
            int tiles = (counts[e] + 127) >> 7;
            for (int i = 0; i < tiles; i++) tile2e[tl++] = e;
            cum += tiles << 7;
        }
        for (int i = tl; i < MAXTILES; i++) tile2e[i] = -1;
        *total_tiles = tl;
    }
    for (int i = threadIdx.x; i < PADPAIRS; i += 256) {
        pair_token[i] = 0;
        pair_gate[i] = 0.f;
    }
}

// ---------------- scatter tokens into per-expert segments ----------------
__global__ __launch_bounds__(256) void scatter_k(const int* __restrict__ tok_idx,
                                                 const float* __restrict__ tok_gate,
                                                 const int* __restrict__ seg_start,
                                                 int* __restrict__ cursor,
                                                 int* __restrict__ pair_token,
                                                 float* __restrict__ pair_gate) {
    int t = blockIdx.x * 256 + threadIdx.x;
#pragma unroll
    for (int s = 0; s < 2; s++) {
        int e = tok_idx[t * 2 + s];
        int pos = seg_start[e] + atomicAdd(&cursor[e], 1);
        pair_token[pos] = t;
        pair_gate[pos] = tok_gate[t * 2 + s];
    }
}

// ---------------- GEMM1: h = gelu(x_gathered @ wfc[e]^T + bfc[e]) ----------------
// tile: 128 pair-rows x 128 f-cols, K = D = 1024, BK = 64
__global__ __launch_bounds__(256) void gemm1_kernel(const unsigned short* __restrict__ xb,
                                                    const unsigned short* __restrict__ wfcb,
                                                    const float* __restrict__ bfc,
                                                    const int* __restrict__ pair_token,
                                                    const int* __restrict__ tile2e,
                                                    int chunk_base,
                                                    unsigned short* __restrict__ h) {
    int tile = chunk_base + blockIdx.y;
    int e = tile2e[tile];
    if (e < 0) return;
    int ftile = blockIdx.x;                      // 0..31

    __shared__ unsigned short sA[128 * 72];      // +8 pad keeps 16B align, breaks conflicts
    __shared__ unsigned short sB[128 * 72];
    __shared__ int sTok[128];

    int tid = threadIdx.x;
    if (tid < 128) sTok[tid] = pair_token[tile * 128 + tid];
    __syncthreads();

    const unsigned short* wB = wfcb + (size_t)e * FDIM * DDIM + (size_t)ftile * 128 * DDIM;

    f32x4 zero = {0.f, 0.f, 0.f, 0.f};
    f32x4 acc[4][4];
#pragma unroll
    for (int i = 0; i < 4; i++)
#pragma unroll
        for (int j = 0; j < 4; j++) acc[i][j] = zero;

    int wave = tid >> 6, lane = tid & 63;
    int wm = (wave >> 1) * 64, wn = (wave & 1) * 64;
    int quad = lane >> 4, l16 = lane & 15;

    for (int k0 = 0; k0 < DDIM; k0 += 64) {
#pragma unroll
        for (int i = 0; i < 4; i++) {
            int idx = tid + i * 256;             // 0..1023
            int row = idx >> 3;                  // 0..127
            int kk = (idx & 7) << 3;             // 0..56
            const unsigned short* srcA = xb + (size_t)sTok[row] * DDIM + k0 + kk;
            *(uint4*)&sA[row * 72 + kk] = *(const uint4*)srcA;
            const unsigned short* srcB = wB + (size_t)row * DDIM + k0 + kk;
            *(uint4*)&sB[row * 72 + kk] = *(const uint4*)srcB;
        }
        __syncthreads();
#pragma unroll
        for (int ks = 0; ks < 64; ks += 32) {
            bf16x8 af[4], bfr[4];
#pragma unroll
            for (int i = 0; i < 4; i++)
                af[i] = *(const bf16x8*)&sA[(wm + i * 16 + l16) * 72 + ks + quad * 8];
#pragma unroll
            for (int j = 0; j < 4; j++)
                bfr[j] = *(const bf16x8*)&sB[(wn + j * 16 + l16) * 72 + ks + quad * 8];
#pragma unroll
            for (int i = 0; i < 4; i++)
#pragma unroll
                for (int j = 0; j < 4; j++)
                    acc[i][j] = __builtin_amdgcn_mfma_f32_16x16x32_bf16(af[i], bfr[j], acc[i][j], 0, 0, 0);
        }
        __syncthreads();
    }

    // epilogue: bias + exact gelu -> bf16 h (chunk-local rows)
    unsigned short* hrow_base = h + (size_t)blockIdx.y * 128 * FDIM;
#pragma unroll
    for (int i = 0; i < 4; i++) {
#pragma unroll
        for (int j = 0; j < 4; j++) {
            int col = wn + j * 16 + l16;
            int f = ftile * 128 + col;
            float bias = bfc[e * FDIM + f];
#pragma unroll
            for (int r = 0; r < 4; r++) {
                int row = wm + i * 16 + quad * 4 + r;
                float v = acc[i][j][r] + bias;
                v = 0.5f * v * (1.f + erff(v * 0.70710678118654752f));
                hrow_base[(size_t)row * FDIM + f] = f2bf(v);
            }
        }
    }
}

// ---------------- GEMM2: out[token] += (h @ wproj[e]^T + bproj[e]) * gate ----------------
// tile: 128 pair-rows x 128 d-cols, K = F = 4096, BK = 64
__global__ __launch_bounds__(256) void gemm2_kernel(const unsigned short* __restrict__ h,
                                                    const unsigned short* __restrict__ wprojb,
                                                    const float* __restrict__ bproj,
                                                    const int* __restrict__ pair_token,
                                                    const float* __restrict__ pair_gate,
                                                    const int* __restrict__ tile2e,
                                                    int chunk_base,
                                                    float* __restrict__ out) {
    int tile = chunk_base + blockIdx.y;
    int e = tile2e[tile];
    if (e < 0) return;
    int dtile = blockIdx.x;                      // 0..7

    __shared__ unsigned short sA[128 * 72];
    __shared__ unsigned short sB[128 * 72];
    __shared__ int sTok[128];
    __shared__ float sGate[128];

    int tid = threadIdx.x;
    if (tid < 128) {
        sTok[tid] = pair_token[tile * 128 + tid];
        sGate[tid] = pair_gate[tile * 128 + tid];
    }
    __syncthreads();

    const unsigned short* hA = h + (size_t)blockIdx.y * 128 * FDIM;
    const unsigned short* wB = wprojb + (size_t)e * DDIM * FDIM + (size_t)dtile * 128 * FDIM;

    f32x4 zero = {0.f, 0.f, 0.f, 0.f};
    f32x4 acc[4][4];
#pragma unroll
    for (int i = 0; i < 4; i++)
#pragma unroll
        for (int j = 0; j < 4; j++) acc[i][j] = zero;

    int wave = tid >> 6, lane = tid & 63;
    int wm = (wave >> 1) * 64, wn = (wave & 1) * 64;
    int quad = lane >> 4, l16 = lane & 15;

    for (int k0 = 0; k0 < FDIM; k0 += 64) {
#pragma unroll
        for (int i = 0; i < 4; i++) {
            int idx = tid + i * 256;
            int row = idx >> 3;
            int kk = (idx & 7) << 3;
            const unsigned short* srcA = hA + (size_t)row * FDIM + k0 + kk;
            *(uint4*)&sA[row * 72 + kk] = *(const uint4*)srcA;
            const unsigned short* srcB = wB + (size_t)row * FDIM + k0 + kk;
            *(uint4*)&sB[row * 72 + kk] = *(const uint4*)srcB;
        }
        __syncthreads();
#pragma unroll
        for (int ks = 0; ks < 64; ks += 32) {
            bf16x8 af[4], bfr[4];
#pragma unroll
            for (int i = 0; i < 4; i++)
                af[i] = *(const bf16x8*)&sA[(wm + i * 16 + l16) * 72 + ks + quad * 8];
#pragma unroll
            for (int j = 0; j < 4; j++)
                bfr[j] = *(const bf16x8*)&sB[(wn + j * 16 + l16) * 72 + ks + quad * 8];
#pragma unroll
            for (int i = 0; i < 4; i++)
#pragma unroll
                for (int j = 0; j < 4; j++)
                    acc[i][j] = __builtin_amdgcn_mfma_f32_16x16x32_bf16(af[i], bfr[j], acc[i][j], 0, 0, 0);
        }
        __syncthreads();
    }

    // epilogue: bias, gate, atomic scatter-add into out (exactly 2 adds/element)
#pragma unroll
    for (int i = 0; i < 4; i++) {
#pragma unroll
        for (int j = 0; j < 4; j++) {
            int col = wn + j * 16 + l16;
            int d = dtile * 128 + col;
            float bias = bproj[e * DDIM + d];
#pragma unroll
            for (int r = 0; r < 4; r++) {
                int row = wm + i * 16 + quad * 4 + r;
                float v = (acc[i][j][r] + bias) * sGate[row];
                atomicAdd(&out[(size_t)sTok[row] * DDIM + d], v);
            }
        }
    }
}

// ---------------- LayerNorm (in-place on out) ----------------
__global__ __launch_bounds__(256) void ln_kernel(float* __restrict__ out,
                                                 const float* __restrict__ g,
                                                 const float* __restrict__ b) {
    __shared__ float s1[4], s2[4];
    int t = blockIdx.x, tid = threadIdx.x;
    float* row = out + (size_t)t * DDIM;
    float4 v = ((const float4*)row)[tid];
    float sum = v.x + v.y + v.z + v.w;
    float sq = v.x * v.x + v.y * v.y + v.z * v.z + v.w * v.w;
#pragma unroll
    for (int off = 32; off > 0; off >>= 1) {
        sum += __shfl_down(sum, off);
        sq  += __shfl_down(sq, off);
    }
    int wave = tid >> 6, lane = tid & 63;
    if (lane == 0) { s1[wave] = sum; s2[wave] = sq; }
    __syncthreads();
    float tot = s1[0] + s1[1] + s1[2] + s1[3];
    float totsq = s2[0] + s2[1] + s2[2] + s2[3];
    float mu = tot * (1.f / DDIM);
    float var = totsq * (1.f / DDIM) - mu * mu;
    float rs = rsqrtf(var + 1e-5f);
    float4 gv = ((const float4*)g)[tid];
    float4 bv = ((const float4*)b)[tid];
    float4 o;
    o.x = (v.x - mu) * rs * gv.x + bv.x;
    o.y = (v.y - mu) * rs * gv.y + bv.y;
    o.z = (v.z - mu) * rs * gv.z + bv.z;
    o.w = (v.w - mu) * rs * gv.w + bv.w;
    ((float4*)row)[tid] = o;
}

extern "C" void kernel_launch(void* const* d_in, const int* in_sizes, int n_in,
                              void* d_out, int out_size, void* d_ws, size_t ws_size,
                              hipStream_t stream) {
    const float* x   = (const float*)d_in[0];
    const float* rw  = (const float*)d_in[1];
    const float* wfc = (const float*)d_in[2];
    const float* bfc = (const float*)d_in[3];
    const float* wpr = (const float*)d_in[4];
    const float* bpr = (const float*)d_in[5];
    const float* lng = (const float*)d_in[6];
    const float* lnb = (const float*)d_in[7];

    float* out = (float*)d_out;                       // [16384,1024]
    float* logits = out + (size_t)NTOK * DDIM;        // [16384,8]

    char* ws = (char*)d_ws;
    unsigned short* xb     = (unsigned short*)(ws + WS_XB);
    unsigned short* wfcb   = (unsigned short*)(ws + WS_WFCB);
    unsigned short* wprojb = (unsigned short*)(ws + WS_WPROJB);
    unsigned short* hbuf   = (unsigned short*)(ws + WS_H);
    int*   ptok  = (int*)(ws + WS_PTOK);
    float* pgate = (float*)(ws + WS_PGATE);
    int*   tidx  = (int*)(ws + WS_TIDX);
    float* tgate = (float*)(ws + WS_TGATE);
    int*   meta  = (int*)(ws + WS_META);
    int* counts = meta;          // 8
    int* cursor = meta + 8;      // 8
    int* segs   = meta + 16;     // 8
    int* total  = meta + 24;     // 1
    int* tile2e = meta + 32;     // 264

    hipMemsetAsync(out, 0, (size_t)NTOK * DDIM * sizeof(float), stream);
    hipMemsetAsync(meta, 0, 64, stream);

    convert_kernel<<<(NEXP * FDIM * DDIM) / 4 / 256, 256, 0, stream>>>(wfc, wfcb);
    convert_kernel<<<(NEXP * DDIM * FDIM) / 4 / 256, 256, 0, stream>>>(wpr, wprojb);
    router_kernel<<<NTOK / 4, 256, 0, stream>>>(x, rw, xb, logits, tidx, tgate, counts);
    seg_plan<<<1, 256, 0, stream>>>(counts, segs, tile2e, total, ptok, pgate);
    scatter_k<<<NTOK / 256, 256, 0, stream>>>(tidx, tgate, segs, cursor, ptok, pgate);

    for (int c = 0; c < NCHUNKS; c++) {
        gemm1_kernel<<<dim3(FDIM / 128, CHUNK_TILES), 256, 0, stream>>>(
            xb, wfcb, bfc, ptok, tile2e, c * CHUNK_TILES, hbuf);
        gemm2_kernel<<<dim3(DDIM / 128, CHUNK_TILES), 256, 0, stream>>>(
            hbuf, wprojb, bpr, ptok, pgate, tile2e, c * CHUNK_TILES, out);
    }
    ln_kernel<<<NTOK, 256, 0, stream>>>(out, lng, lnb);
}

// Round 2
// 1815.690 us; speedup vs baseline: 1.2388x; 1.2388x over previous
//
#include <hip/hip_runtime.h>

// Problem constants (B=8, T=2048 -> NTOK=16384; D=1024, E=8, F=4096, top_k=2)
#define NTOK 16384
#define DDIM 1024
#define FDIM 4096
#define NEXP 8
#define PADPAIRS 33792          // 264 * 128 (worst-case 128-padded segments)
#define MAXTILES 264
#define CHUNK_TILES 66
#define NCHUNKS 4
#define CHUNK_ROWS (CHUNK_TILES * 128)

// Workspace layout (bytes)
#define WS_XB      0ull                    // bf16 x       [NTOK][D]      33,554,432
#define WS_WFCB    33554432ull             // bf16 wfc     [E][F][D]      67,108,864
#define WS_WPROJB  100663296ull            // bf16 wproj   [E][D][F]      67,108,864
#define WS_H       167772160ull            // bf16 h       [CHUNK_ROWS][F] 69,206,016
#define WS_PTOK    236978176ull            // int  pair_token [PADPAIRS]
#define WS_PGATE   237113344ull            // f32  pair_gate  [PADPAIRS]
#define WS_TIDX    237248512ull            // int  tok_idx  [NTOK][2]
#define WS_TGATE   237379584ull            // f32  tok_gate [NTOK][2]
#define WS_META    237510656ull            // ints: counts[8] cursor[8] seg[8] total[1] pad, tile2e[264]

typedef short bf16x8 __attribute__((ext_vector_type(8)));
typedef float f32x4 __attribute__((ext_vector_type(4)));

__device__ __forceinline__ unsigned short f2bf(float f) {
    unsigned int u = __float_as_uint(f);
    u += 0x7fffu + ((u >> 16) & 1u);   // round to nearest even
    return (unsigned short)(u >> 16);
}

// CK-style async global->LDS direct load, 16B per lane.
// LDS dest = wave-uniform base + lane*16; global addr is per-lane.
__device__ __forceinline__ void gload16(const unsigned short* g, const unsigned short* lds) {
    __builtin_amdgcn_global_load_lds(
        (const __attribute__((address_space(1))) unsigned int*)(unsigned long long)(const void*)g,
        (__attribute__((address_space(3))) unsigned int*)(unsigned int)(unsigned long long)(const void*)lds,
        16, 0, 0);
}

// ---------------- fp32 -> bf16 weight conversion ----------------
__global__ __launch_bounds__(256) void convert_kernel(const float* __restrict__ src,
                                                      unsigned short* __restrict__ dst) {
    int i = blockIdx.x * 256 + threadIdx.x;     // one float4 per thread
    float4 v = ((const float4*)src)[i];
    ushort4 o;
    o.x = f2bf(v.x); o.y = f2bf(v.y); o.z = f2bf(v.z); o.w = f2bf(v.w);
    ((ushort4*)dst)[i] = o;
}

// ---------------- router: logits (fp32), top-2 + softmax gates, x->bf16 ----------------
// 16 tokens/block (4/wave), float4 loads, ushort4 stores, LDS-aggregated counts.
__global__ __launch_bounds__(256) void router_kernel(const float* __restrict__ x,
                                                     const float* __restrict__ rw,
                                                     unsigned short* __restrict__ xb,
                                                     float* __restrict__ logits,
                                                     int* __restrict__ tok_idx,
                                                     float* __restrict__ tok_gate,
                                                     int* __restrict__ counts) {
    __shared__ float srw[NEXP * DDIM];          // 32 KiB
    __shared__ int scnt[NEXP];
    int tid = threadIdx.x;
    if (tid < NEXP) scnt[tid] = 0;
    for (int i = tid; i < NEXP * DDIM / 4; i += 256)
        ((float4*)srw)[i] = ((const float4*)rw)[i];
    __syncthreads();

    int wave = tid >> 6, lane = tid & 63;
    const float4* srw4 = (const float4*)srw;

    for (int j = 0; j < 4; j++) {
        int t = blockIdx.x * 16 + wave * 4 + j;
        const float4* xr = (const float4*)(x + (size_t)t * DDIM);
        ushort4* xbr = (ushort4*)(xb + (size_t)t * DDIM);

        float acc[NEXP];
#pragma unroll
        for (int e = 0; e < NEXP; e++) acc[e] = 0.f;

#pragma unroll
        for (int i = 0; i < 4; i++) {
            int k4 = i * 64 + lane;
            float4 xv = xr[k4];
            ushort4 o;
            o.x = f2bf(xv.x); o.y = f2bf(xv.y); o.z = f2bf(xv.z); o.w = f2bf(xv.w);
            xbr[k4] = o;
#pragma unroll
            for (int e = 0; e < NEXP; e++) {
                float4 wv = srw4[e * 256 + k4];
                acc[e] += xv.x * wv.x + xv.y * wv.y + xv.z * wv.z + xv.w * wv.w;
            }
        }
#pragma unroll
        for (int off = 1; off < 64; off <<= 1) {
#pragma unroll
            for (int e = 0; e < NEXP; e++) acc[e] += __shfl_xor(acc[e], off);
        }
        if (lane == 0) {
            float v0 = -1e30f, v1 = -1e30f; int i0 = 0, i1 = 0;
#pragma unroll
            for (int e = 0; e < NEXP; e++) {
                float v = acc[e];
                logits[(size_t)t * NEXP + e] = v;
                if (v > v0)      { v1 = v0; i1 = i0; v0 = v; i0 = e; }
                else if (v > v1) { v1 = v;  i1 = e; }
            }
            float d = __expf(v1 - v0);              // <= 1, stable
            float g0 = 1.f / (1.f + d);
            float g1 = d * g0;
            tok_idx[t * 2 + 0] = i0; tok_idx[t * 2 + 1] = i1;
            tok_gate[t * 2 + 0] = g0; tok_gate[t * 2 + 1] = g1;
            atomicAdd(&scnt[i0], 1);
            atomicAdd(&scnt[i1], 1);
        }
    }
    __syncthreads();
    if (tid < NEXP) atomicAdd(&counts[tid], scnt[tid]);
}

// ---------------- segment planning + pair-array padding init ----------------
__global__ void seg_plan(const int* __restrict__ counts, int* __restrict__ seg_start,
                         int* __restrict__ tile2e, int* __restrict__ total_tiles,
                         int* __restrict__ pair_token, float* __restrict__ pair_gate) {
    if (threadIdx.x == 0) {
        int cum = 0, tl = 0;
        for (int e = 0; e < NEXP; e++) {
            seg_start[e] = cum;
            int tiles = (counts[e] + 127) >> 7;
            for (int i = 0; i < tiles; i++) tile2e[tl++] = e;
            cum += tiles << 7;
        }
        for (int i = tl; i < MAXTILES; i++) tile2e[i] = -1;
        *total_tiles = tl;
    }
    for (int i = threadIdx.x; i < PADPAIRS; i += 256) {
        pair_token[i] = 0;
        pair_gate[i] = 0.f;
    }
}

// ---------------- scatter tokens into per-expert segments ----------------
__global__ __launch_bounds__(256) void scatter_k(const int* __restrict__ tok_idx,
                                                 const float* __restrict__ tok_gate,
                                                 const int* __restrict__ seg_start,
                                                 int* __restrict__ cursor,
                                                 int* __restrict__ pair_token,
                                                 float* __restrict__ pair_gate) {
    int t = blockIdx.x * 256 + threadIdx.x;
#pragma unroll
    for (int s = 0; s < 2; s++) {
        int e = tok_idx[t * 2 + s];
        int pos = seg_start[e] + atomicAdd(&cursor[e], 1);
        pair_token[pos] = t;
        pair_gate[pos] = tok_gate[t * 2 + s];
    }
}

// ---------------- GEMM1: h = gelu(x_gathered @ wfc[e]^T + bfc[e]) ----------------
// 128x128 tile, K=D=1024, BK=64, global_load_lds staging, XOR-swizzled LDS.
__global__ __launch_bounds__(256) void gemm1_kernel(const unsigned short* __restrict__ xb,
                                                    const unsigned short* __restrict__ wfcb,
                                                    const float* __restrict__ bfc,
                                                    const int* __restrict__ pair_token,
                                                    const int* __restrict__ tile2e,
                                                    int chunk_base,
                                                    unsigned short* __restrict__ h) {
    int tile = chunk_base + blockIdx.y;
    int e = tile2e[tile];
    if (e < 0) return;
    int ftile = blockIdx.x;                      // 0..31

    __shared__ unsigned short sA[128 * 64];      // no pad (global_load_lds constraint)
    __shared__ unsigned short sB[128 * 64];
    __shared__ int sTok[128];

    int tid = threadIdx.x;
    if (tid < 128) sTok[tid] = pair_token[tile * 128 + tid];
    __syncthreads();

    int wave = tid >> 6, lane = tid & 63;
    int lrow = lane >> 3;                        // 0..7
    int kblk = (lane & 7) ^ lrow;                // swizzled source k-block

    const unsigned short* wB = wfcb + (size_t)e * FDIM * DDIM + (size_t)ftile * 128 * DDIM;
    const unsigned short* aBase[4];
    const unsigned short* bBase[4];
#pragma unroll
    for (int t = 0; t < 4; t++) {
        int row = wave * 32 + t * 8 + lrow;
        aBase[t] = xb + (size_t)sTok[row] * DDIM + kblk * 8;
        bBase[t] = wB + (size_t)row * DDIM + kblk * 8;
    }

    f32x4 zero = {0.f, 0.f, 0.f, 0.f};
    f32x4 acc[4][4];
#pragma unroll
    for (int i = 0; i < 4; i++)
#pragma unroll
        for (int j = 0; j < 4; j++) acc[i][j] = zero;

    int wm = (wave >> 1) * 64, wn = (wave & 1) * 64;
    int quad = lane >> 4, l16 = lane & 15;
    int r7 = l16 & 7;

    for (int k0 = 0; k0 < DDIM; k0 += 64) {
#pragma unroll
        for (int t = 0; t < 4; t++) {
            gload16(aBase[t], &sA[(wave * 32 + t * 8) * 64]);
            gload16(bBase[t], &sB[(wave * 32 + t * 8) * 64]);
            aBase[t] += 64; bBase[t] += 64;
        }
        __syncthreads();
#pragma unroll
        for (int ks = 0; ks < 64; ks += 32) {
            int g = (ks >> 3) + quad;            // global k-block 0..7
            bf16x8 af[4], bfr[4];
#pragma unroll
            for (int i = 0; i < 4; i++) {
                int row = wm + i * 16 + l16;
                af[i] = *(const bf16x8*)&sA[row * 64 + ((g ^ r7) << 3)];
            }
#pragma unroll
            for (int j = 0; j < 4; j++) {
                int row = wn + j * 16 + l16;
                bfr[j] = *(const bf16x8*)&sB[row * 64 + ((g ^ r7) << 3)];
            }
#pragma unroll
            for (int i = 0; i < 4; i++)
#pragma unroll
                for (int j = 0; j < 4; j++)
                    acc[i][j] = __builtin_amdgcn_mfma_f32_16x16x32_bf16(af[i], bfr[j], acc[i][j], 0, 0, 0);
        }
        __syncthreads();
    }

    // epilogue: bias + exact gelu -> bf16 h (chunk-local rows)
    unsigned short* hrow_base = h + (size_t)blockIdx.y * 128 * FDIM;
#pragma unroll
    for (int i = 0; i < 4; i++) {
#pragma unroll
        for (int j = 0; j < 4; j++) {
            int col = wn + j * 16 + l16;
            int f = ftile * 128 + col;
            float bias = bfc[e * FDIM + f];
#pragma unroll
            for (int r = 0; r < 4; r++) {
                int row = wm + i * 16 + quad * 4 + r;
                float v = acc[i][j][r] + bias;
                v = 0.5f * v * (1.f + erff(v * 0.70710678118654752f));
                hrow_base[(size_t)row * FDIM + f] = f2bf(v);
            }
        }
    }
}

// ---------------- GEMM2: out[token] += (h @ wproj[e]^T + bproj[e]) * gate ----------------
// 128x128 tile, K=F=4096, BK=64, global_load_lds staging, XOR-swizzled LDS.
__global__ __launch_bounds__(256) void gemm2_kernel(const unsigned short* __restrict__ h,
                                                    const unsigned short* __restrict__ wprojb,
                                                    const float* __restrict__ bproj,
                                                    const int* __restrict__ pair_token,
                                                    const float* __restrict__ pair_gate,
                                                    const int* __restrict__ tile2e,
                                                    int chunk_base,
                                                    float* __restrict__ out) {
    int tile = chunk_base + blockIdx.y;
    int e = tile2e[tile];
    if (e < 0) return;
    int dtile = blockIdx.x;                      // 0..7

    __shared__ unsigned short sA[128 * 64];
    __shared__ unsigned short sB[128 * 64];
    __shared__ int sTok[128];
    __shared__ float sGate[128];

    int tid = threadIdx.x;
    if (tid < 128) {
        sTok[tid] = pair_token[tile * 128 + tid];
        sGate[tid] = pair_gate[tile * 128 + tid];
    }
    __syncthreads();

    int wave = tid >> 6, lane = tid & 63;
    int lrow = lane >> 3;
    int kblk = (lane & 7) ^ lrow;

    const unsigned short* hA = h + (size_t)blockIdx.y * 128 * FDIM;
    const unsigned short* wB = wprojb + (size_t)e * DDIM * FDIM + (size_t)dtile * 128 * FDIM;
    const unsigned short* aBase[4];
    const unsigned short* bBase[4];
#pragma unroll
    for (int t = 0; t < 4; t++) {
        int row = wave * 32 + t * 8 + lrow;
        aBase[t] = hA + (size_t)row * FDIM + kblk * 8;
        bBase[t] = wB + (size_t)row * FDIM + kblk * 8;
    }

    f32x4 zero = {0.f, 0.f, 0.f, 0.f};
    f32x4 acc[4][4];
#pragma unroll
    for (int i = 0; i < 4; i++)
#pragma unroll
        for (int j = 0; j < 4; j++) acc[i][j] = zero;

    int wm = (wave >> 1) * 64, wn = (wave & 1) * 64;
    int quad = lane >> 4, l16 = lane & 15;
    int r7 = l16 & 7;

    for (int k0 = 0; k0 < FDIM; k0 += 64) {
#pragma unroll
        for (int t = 0; t < 4; t++) {
            gload16(aBase[t], &sA[(wave * 32 + t * 8) * 64]);
            gload16(bBase[t], &sB[(wave * 32 + t * 8) * 64]);
            aBase[t] += 64; bBase[t] += 64;
        }
        __syncthreads();
#pragma unroll
        for (int ks = 0; ks < 64; ks += 32) {
            int g = (ks >> 3) + quad;
            bf16x8 af[4], bfr[4];
#pragma unroll
            for (int i = 0; i < 4; i++) {
                int row = wm + i * 16 + l16;
                af[i] = *(const bf16x8*)&sA[row * 64 + ((g ^ r7) << 3)];
            }
#pragma unroll
            for (int j = 0; j < 4; j++) {
                int row = wn + j * 16 + l16;
                bfr[j] = *(const bf16x8*)&sB[row * 64 + ((g ^ r7) << 3)];
            }
#pragma unroll
            for (int i = 0; i < 4; i++)
#pragma unroll
                for (int j = 0; j < 4; j++)
                    acc[i][j] = __builtin_amdgcn_mfma_f32_16x16x32_bf16(af[i], bfr[j], acc[i][j], 0, 0, 0);
        }
        __syncthreads();
    }

    // epilogue: bias, gate, atomic scatter-add into out (exactly 2 adds/element)
#pragma unroll
    for (int i = 0; i < 4; i++) {
#pragma unroll
        for (int j = 0; j < 4; j++) {
            int col = wn + j * 16 + l16;
            int d = dtile * 128 + col;
            float bias = bproj[e * DDIM + d];
#pragma unroll
            for (int r = 0; r < 4; r++) {
                int row = wm + i * 16 + quad * 4 + r;
                float v = (acc[i][j][r] + bias) * sGate[row];
                atomicAdd(&out[(size_t)sTok[row] * DDIM + d], v);
            }
        }
    }
}

// ---------------- LayerNorm (in-place on out) ----------------
__global__ __launch_bounds__(256) void ln_kernel(float* __restrict__ out,
                                                 const float* __restrict__ g,
                                                 const float* __restrict__ b) {
    __shared__ float s1[4], s2[4];
    int t = blockIdx.x, tid = threadIdx.x;
    float* row = out + (size_t)t * DDIM;
    float4 v = ((const float4*)row)[tid];
    float sum = v.x + v.y + v.z + v.w;
    float sq = v.x * v.x + v.y * v.y + v.z * v.z + v.w * v.w;
#pragma unroll
    for (int off = 32; off > 0; off >>= 1) {
        sum += __shfl_down(sum, off);
        sq  += __shfl_down(sq, off);
    }
    int wave = tid >> 6, lane = tid & 63;
    if (lane == 0) { s1[wave] = sum; s2[wave] = sq; }
    __syncthreads();
    float tot = s1[0] + s1[1] + s1[2] + s1[3];
    float totsq = s2[0] + s2[1] + s2[2] + s2[3];
    float mu = tot * (1.f / DDIM);
    float var = totsq * (1.f / DDIM) - mu * mu;
    float rs = rsqrtf(var + 1e-5f);
    float4 gv = ((const float4*)g)[tid];
    float4 bv = ((const float4*)b)[tid];
    float4 o;
    o.x = (v.x - mu) * rs * gv.x + bv.x;
    o.y = (v.y - mu) * rs * gv.y + bv.y;
    o.z = (v.z - mu) * rs * gv.z + bv.z;
    o.w = (v.w - mu) * rs * gv.w + bv.w;
    ((float4*)row)[tid] = o;
}

extern "C" void kernel_launch(void* const* d_in, const int* in_sizes, int n_in,
                              void* d_out, int out_size, void* d_ws, size_t ws_size,
                              hipStream_t stream) {
    const float* x   = (const float*)d_in[0];
    const float* rw  = (const float*)d_in[1];
    const float* wfc = (const float*)d_in[2];
    const float* bfc = (const float*)d_in[3];
    const float* wpr = (const float*)d_in[4];
    const float* bpr = (const float*)d_in[5];
    const float* lng = (const float*)d_in[6];
    const float* lnb = (const float*)d_in[7];

    float* out = (float*)d_out;                       // [16384,1024]
    float* logits = out + (size_t)NTOK * DDIM;        // [16384,8]

    char* ws = (char*)d_ws;
    unsigned short* xb     = (unsigned short*)(ws + WS_XB);
    unsigned short* wfcb   = (unsigned short*)(ws + WS_WFCB);
    unsigned short* wprojb = (unsigned short*)(ws + WS_WPROJB);
    unsigned short* hbuf   = (unsigned short*)(ws + WS_H);
    int*   ptok  = (int*)(ws + WS_PTOK);
    float* pgate = (float*)(ws + WS_PGATE);
    int*   tidx  = (int*)(ws + WS_TIDX);
    float* tgate = (float*)(ws + WS_TGATE);
    int*   meta  = (int*)(ws + WS_META);
    int* counts = meta;          // 8
    int* cursor = meta + 8;      // 8
    int* segs   = meta + 16;     // 8
    int* total  = meta + 24;     // 1
    int* tile2e = meta + 32;     // 264

    hipMemsetAsync(out, 0, (size_t)NTOK * DDIM * sizeof(float), stream);
    hipMemsetAsync(meta, 0, 64, stream);

    convert_kernel<<<(NEXP * FDIM * DDIM) / 4 / 256, 256, 0, stream>>>(wfc, wfcb);
    convert_kernel<<<(NEXP * DDIM * FDIM) / 4 / 256, 256, 0, stream>>>(wpr, wprojb);
    router_kernel<<<NTOK / 16, 256, 0, stream>>>(x, rw, xb, logits, tidx, tgate, counts);
    seg_plan<<<1, 256, 0, stream>>>(counts, segs, tile2e, total, ptok, pgate);
    scatter_k<<<NTOK / 256, 256, 0, stream>>>(tidx, tgate, segs, cursor, ptok, pgate);

    for (int c = 0; c < NCHUNKS; c++) {
        gemm1_kernel<<<dim3(FDIM / 128, CHUNK_TILES), 256, 0, stream>>>(
            xb, wfcb, bfc, ptok, tile2e, c * CHUNK_TILES, hbuf);
        gemm2_kernel<<<dim3(DDIM / 128, CHUNK_TILES), 256, 0, stream>>>(
            hbuf, wprojb, bpr, ptok, pgate, tile2e, c * CHUNK_TILES, out);
    }
    ln_kernel<<<NTOK, 256, 0, stream>>>(out, lng, lnb);
}

// Round 3
// 1555.306 us; speedup vs baseline: 1.4462x; 1.1674x over previous
//
#include <hip/hip_runtime.h>

// Problem constants (B=8, T=2048 -> NTOK=16384; D=1024, E=8, F=4096, top_k=2)
#define NTOK 16384
#define DDIM 1024
#define FDIM 4096
#define NEXP 8
#define PADPAIRS 33792          // 264 * 128 (worst-case 128-padded segments)
#define MAXTILES 264

// Fixed workspace layout (bytes); h + aux are placed dynamically after these.
#define WS_XB      0ull                    // bf16 x       [NTOK][D]      33,554,432
#define WS_WFCB    33554432ull             // bf16 wfc     [E][F][D]      67,108,864
#define WS_WPROJB  100663296ull            // bf16 wproj   [E][D][F]      67,108,864
#define WS_H       167772160ull            // bf16 h       [ct*128][F]    (dynamic)

typedef short bf16x8 __attribute__((ext_vector_type(8)));
typedef float f32x4 __attribute__((ext_vector_type(4)));

__device__ __forceinline__ unsigned short f2bf(float f) {
    unsigned int u = __float_as_uint(f);
    u += 0x7fffu + ((u >> 16) & 1u);   // round to nearest even
    return (unsigned short)(u >> 16);
}

// CK-style async global->LDS direct load, 16B per lane.
// LDS dest = wave-uniform base + lane*16; global addr is per-lane.
__device__ __forceinline__ void gload16(const unsigned short* g, const unsigned short* lds) {
    __builtin_amdgcn_global_load_lds(
        (const __attribute__((address_space(1))) unsigned int*)(unsigned long long)(const void*)g,
        (__attribute__((address_space(3))) unsigned int*)(unsigned int)(unsigned long long)(const void*)lds,
        16, 0, 0);
}

// ---------------- fp32 -> bf16 weight conversion ----------------
__global__ __launch_bounds__(256) void convert_kernel(const float* __restrict__ src,
                                                      unsigned short* __restrict__ dst) {
    int i = blockIdx.x * 256 + threadIdx.x;     // one float4 per thread
    float4 v = ((const float4*)src)[i];
    ushort4 o;
    o.x = f2bf(v.x); o.y = f2bf(v.y); o.z = f2bf(v.z); o.w = f2bf(v.w);
    ((ushort4*)dst)[i] = o;
}

// ---------------- router: logits (fp32), top-2 + softmax gates, x->bf16 ----------------
__global__ __launch_bounds__(256) void router_kernel(const float* __restrict__ x,
                                                     const float* __restrict__ rw,
                                                     unsigned short* __restrict__ xb,
                                                     float* __restrict__ logits,
                                                     int* __restrict__ tok_idx,
                                                     float* __restrict__ tok_gate,
                                                     int* __restrict__ counts) {
    __shared__ float srw[NEXP * DDIM];          // 32 KiB
    __shared__ int scnt[NEXP];
    int tid = threadIdx.x;
    if (tid < NEXP) scnt[tid] = 0;
    for (int i = tid; i < NEXP * DDIM / 4; i += 256)
        ((float4*)srw)[i] = ((const float4*)rw)[i];
    __syncthreads();

    int wave = tid >> 6, lane = tid & 63;
    const float4* srw4 = (const float4*)srw;

    for (int j = 0; j < 4; j++) {
        int t = blockIdx.x * 16 + wave * 4 + j;
        const float4* xr = (const float4*)(x + (size_t)t * DDIM);
        ushort4* xbr = (ushort4*)(xb + (size_t)t * DDIM);

        float acc[NEXP];
#pragma unroll
        for (int e = 0; e < NEXP; e++) acc[e] = 0.f;

#pragma unroll
        for (int i = 0; i < 4; i++) {
            int k4 = i * 64 + lane;
            float4 xv = xr[k4];
            ushort4 o;
            o.x = f2bf(xv.x); o.y = f2bf(xv.y); o.z = f2bf(xv.z); o.w = f2bf(xv.w);
            xbr[k4] = o;
#pragma unroll
            for (int e = 0; e < NEXP; e++) {
                float4 wv = srw4[e * 256 + k4];
                acc[e] += xv.x * wv.x + xv.y * wv.y + xv.z * wv.z + xv.w * wv.w;
            }
        }
#pragma unroll
        for (int off = 1; off < 64; off <<= 1) {
#pragma unroll
            for (int e = 0; e < NEXP; e++) acc[e] += __shfl_xor(acc[e], off);
        }
        if (lane == 0) {
            float v0 = -1e30f, v1 = -1e30f; int i0 = 0, i1 = 0;
#pragma unroll
            for (int e = 0; e < NEXP; e++) {
                float v = acc[e];
                logits[(size_t)t * NEXP + e] = v;
                if (v > v0)      { v1 = v0; i1 = i0; v0 = v; i0 = e; }
                else if (v > v1) { v1 = v;  i1 = e; }
            }
            float d = __expf(v1 - v0);              // <= 1, stable
            float g0 = 1.f / (1.f + d);
            float g1 = d * g0;
            tok_idx[t * 2 + 0] = i0; tok_idx[t * 2 + 1] = i1;
            tok_gate[t * 2 + 0] = g0; tok_gate[t * 2 + 1] = g1;
            atomicAdd(&scnt[i0], 1);
            atomicAdd(&scnt[i1], 1);
        }
    }
    __syncthreads();
    if (tid < NEXP) atomicAdd(&counts[tid], scnt[tid]);
}

// ---------------- segment planning + pair-array padding init ----------------
__global__ void seg_plan(const int* __restrict__ counts, int* __restrict__ seg_start,
                         int* __restrict__ tile2e, int* __restrict__ total_tiles,
                         int* __restrict__ pair_token, float* __restrict__ pair_gate) {
    if (threadIdx.x == 0) {
        int cum = 0, tl = 0;
        for (int e = 0; e < NEXP; e++) {
            seg_start[e] = cum;
            int tiles = (counts[e] + 127) >> 7;
            for (int i = 0; i < tiles; i++) tile2e[tl++] = e;
            cum += tiles << 7;
        }
        for (int i = tl; i < MAXTILES; i++) tile2e[i] = -1;
        *total_tiles = tl;
    }
    for (int i = threadIdx.x; i < PADPAIRS; i += 256) {
        pair_token[i] = 0;
        pair_gate[i] = 0.f;
    }
}

// ---------------- scatter tokens into per-expert segments ----------------
__global__ __launch_bounds__(256) void scatter_k(const int* __restrict__ tok_idx,
                                                 const float* __restrict__ tok_gate,
                                                 const int* __restrict__ seg_start,
                                                 int* __restrict__ cursor,
                                                 int* __restrict__ pair_token,
                                                 float* __restrict__ pair_gate) {
    int t = blockIdx.x * 256 + threadIdx.x;
#pragma unroll
    for (int s = 0; s < 2; s++) {
        int e = tok_idx[t * 2 + s];
        int pos = seg_start[e] + atomicAdd(&cursor[e], 1);
        pair_token[pos] = t;
        pair_gate[pos] = tok_gate[t * 2 + s];
    }
}

// ---------------- GEMM1: h = gelu(x_gathered @ wfc[e]^T + bfc[e]) ----------------
// 128x128 tile, K=D=1024, BK=64, global_load_lds staging, XOR-swizzled LDS.
// LDS exactly 32 KB -> 5 blocks/CU.
__global__ __launch_bounds__(256) void gemm1_kernel(const unsigned short* __restrict__ xb,
                                                    const unsigned short* __restrict__ wfcb,
                                                    const float* __restrict__ bfc,
                                                    const int* __restrict__ pair_token,
                                                    const int* __restrict__ tile2e,
                                                    int chunk_base,
                                                    unsigned short* __restrict__ h) {
    int tile = chunk_base + blockIdx.y;
    int e = tile2e[tile];
    if (e < 0) return;
    int ftile = blockIdx.x;                      // 0..31

    __shared__ unsigned short sA[128 * 64];      // no pad (global_load_lds constraint)
    __shared__ unsigned short sB[128 * 64];      // total 32768 B

    int tid = threadIdx.x;
    int wave = tid >> 6, lane = tid & 63;
    int lrow = lane >> 3;                        // 0..7
    int kblk = (lane & 7) ^ lrow;                // swizzled source k-block

    const unsigned short* wB = wfcb + (size_t)e * FDIM * DDIM + (size_t)ftile * 128 * DDIM;
    const unsigned short* aBase[4];
    const unsigned short* bBase[4];
#pragma unroll
    for (int t = 0; t < 4; t++) {
        int row = wave * 32 + t * 8 + lrow;
        aBase[t] = xb + (size_t)pair_token[tile * 128 + row] * DDIM + kblk * 8;
        bBase[t] = wB + (size_t)row * DDIM + kblk * 8;
    }

    f32x4 zero = {0.f, 0.f, 0.f, 0.f};
    f32x4 acc[4][4];
#pragma unroll
    for (int i = 0; i < 4; i++)
#pragma unroll
        for (int j = 0; j < 4; j++) acc[i][j] = zero;

    int wm = (wave >> 1) * 64, wn = (wave & 1) * 64;
    int quad = lane >> 4, l16 = lane & 15;
    int r7 = l16 & 7;

    for (int k0 = 0; k0 < DDIM; k0 += 64) {
#pragma unroll
        for (int t = 0; t < 4; t++) {
            gload16(aBase[t], &sA[(wave * 32 + t * 8) * 64]);
            gload16(bBase[t], &sB[(wave * 32 + t * 8) * 64]);
            aBase[t] += 64; bBase[t] += 64;
        }
        __syncthreads();
#pragma unroll
        for (int ks = 0; ks < 64; ks += 32) {
            int g = (ks >> 3) + quad;            // global k-block 0..7
            bf16x8 af[4], bfr[4];
#pragma unroll
            for (int i = 0; i < 4; i++) {
                int row = wm + i * 16 + l16;
                af[i] = *(const bf16x8*)&sA[row * 64 + ((g ^ r7) << 3)];
            }
#pragma unroll
            for (int j = 0; j < 4; j++) {
                int row = wn + j * 16 + l16;
                bfr[j] = *(const bf16x8*)&sB[row * 64 + ((g ^ r7) << 3)];
            }
#pragma unroll
            for (int i = 0; i < 4; i++)
#pragma unroll
                for (int j = 0; j < 4; j++)
                    acc[i][j] = __builtin_amdgcn_mfma_f32_16x16x32_bf16(af[i], bfr[j], acc[i][j], 0, 0, 0);
        }
        __syncthreads();
    }

    // epilogue: bias + exact gelu -> bf16 h (chunk-local rows)
    unsigned short* hrow_base = h + (size_t)blockIdx.y * 128 * FDIM;
#pragma unroll
    for (int i = 0; i < 4; i++) {
#pragma unroll
        for (int j = 0; j < 4; j++) {
            int col = wn + j * 16 + l16;
            int f = ftile * 128 + col;
            float bias = bfc[e * FDIM + f];
#pragma unroll
            for (int r = 0; r < 4; r++) {
                int row = wm + i * 16 + quad * 4 + r;
                float v = acc[i][j][r] + bias;
                v = 0.5f * v * (1.f + erff(v * 0.70710678118654752f));
                hrow_base[(size_t)row * FDIM + f] = f2bf(v);
            }
        }
    }
}

// ---------------- GEMM2: out[token] += (h @ wproj[e]^T + bproj[e]) * gate ----------------
// 128x128 tile, K=F=4096, BK=64, global_load_lds staging, XOR-swizzled LDS.
__global__ __launch_bounds__(256) void gemm2_kernel(const unsigned short* __restrict__ h,
                                                    const unsigned short* __restrict__ wprojb,
                                                    const float* __restrict__ bproj,
                                                    const int* __restrict__ pair_token,
                                                    const float* __restrict__ pair_gate,
                                                    const int* __restrict__ tile2e,
                                                    int chunk_base,
                                                    float* __restrict__ out) {
    int tile = chunk_base + blockIdx.y;
    int e = tile2e[tile];
    if (e < 0) return;
    int dtile = blockIdx.x;                      // 0..7

    __shared__ unsigned short sA[128 * 64];
    __shared__ unsigned short sB[128 * 64];      // total 32768 B

    int tid = threadIdx.x;
    int wave = tid >> 6, lane = tid & 63;
    int lrow = lane >> 3;
    int kblk = (lane & 7) ^ lrow;

    const unsigned short* hA = h + (size_t)blockIdx.y * 128 * FDIM;
    const unsigned short* wB = wprojb + (size_t)e * DDIM * FDIM + (size_t)dtile * 128 * FDIM;
    const unsigned short* aBase[4];
    const unsigned short* bBase[4];
#pragma unroll
    for (int t = 0; t < 4; t++) {
        int row = wave * 32 + t * 8 + lrow;
        aBase[t] = hA + (size_t)row * FDIM + kblk * 8;
        bBase[t] = wB + (size_t)row * FDIM + kblk * 8;
    }

    f32x4 zero = {0.f, 0.f, 0.f, 0.f};
    f32x4 acc[4][4];
#pragma unroll
    for (int i = 0; i < 4; i++)
#pragma unroll
        for (int j = 0; j < 4; j++) acc[i][j] = zero;

    int wm = (wave >> 1) * 64, wn = (wave & 1) * 64;
    int quad = lane >> 4, l16 = lane & 15;
    int r7 = l16 & 7;

    for (int k0 = 0; k0 < FDIM; k0 += 64) {
#pragma unroll
        for (int t = 0; t < 4; t++) {
            gload16(aBase[t], &sA[(wave * 32 + t * 8) * 64]);
            gload16(bBase[t], &sB[(wave * 32 + t * 8) * 64]);
            aBase[t] += 64; bBase[t] += 64;
        }
        __syncthreads();
#pragma unroll
        for (int ks = 0; ks < 64; ks += 32) {
            int g = (ks >> 3) + quad;
            bf16x8 af[4], bfr[4];
#pragma unroll
            for (int i = 0; i < 4; i++) {
                int row = wm + i * 16 + l16;
                af[i] = *(const bf16x8*)&sA[row * 64 + ((g ^ r7) << 3)];
            }
#pragma unroll
            for (int j = 0; j < 4; j++) {
                int row = wn + j * 16 + l16;
                bfr[j] = *(const bf16x8*)&sB[row * 64 + ((g ^ r7) << 3)];
            }
#pragma unroll
            for (int i = 0; i < 4; i++)
#pragma unroll
                for (int j = 0; j < 4; j++)
                    acc[i][j] = __builtin_amdgcn_mfma_f32_16x16x32_bf16(af[i], bfr[j], acc[i][j], 0, 0, 0);
        }
        __syncthreads();
    }

    // epilogue: bias, gate, atomic scatter-add into out (exactly 2 adds/element)
#pragma unroll
    for (int i = 0; i < 4; i++) {
#pragma unroll
        for (int j = 0; j < 4; j++) {
            int col = wn + j * 16 + l16;
            int d = dtile * 128 + col;
            float bias = bproj[e * DDIM + d];
#pragma unroll
            for (int r = 0; r < 4; r++) {
                int row = wm + i * 16 + quad * 4 + r;
                int tok = pair_token[tile * 128 + row];     // L1-cached
                float gate = pair_gate[tile * 128 + row];
                float v = (acc[i][j][r] + bias) * gate;
                atomicAdd(&out[(size_t)tok * DDIM + d], v);
            }
        }
    }
}

// ---------------- LayerNorm (in-place on out) ----------------
__global__ __launch_bounds__(256) void ln_kernel(float* __restrict__ out,
                                                 const float* __restrict__ g,
                                                 const float* __restrict__ b) {
    __shared__ float s1[4], s2[4];
    int t = blockIdx.x, tid = threadIdx.x;
    float* row = out + (size_t)t * DDIM;
    float4 v = ((const float4*)row)[tid];
    float sum = v.x + v.y + v.z + v.w;
    float sq = v.x * v.x + v.y * v.y + v.z * v.z + v.w * v.w;
#pragma unroll
    for (int off = 32; off > 0; off >>= 1) {
        sum += __shfl_down(sum, off);
        sq  += __shfl_down(sq, off);
    }
    int wave = tid >> 6, lane = tid & 63;
    if (lane == 0) { s1[wave] = sum; s2[wave] = sq; }
    __syncthreads();
    float tot = s1[0] + s1[1] + s1[2] + s1[3];
    float totsq = s2[0] + s2[1] + s2[2] + s2[3];
    float mu = tot * (1.f / DDIM);
    float var = totsq * (1.f / DDIM) - mu * mu;
    float rs = rsqrtf(var + 1e-5f);
    float4 gv = ((const float4*)g)[tid];
    float4 bv = ((const float4*)b)[tid];
    float4 o;
    o.x = (v.x - mu) * rs * gv.x + bv.x;
    o.y = (v.y - mu) * rs * gv.y + bv.y;
    o.z = (v.z - mu) * rs * gv.z + bv.z;
    o.w = (v.w - mu) * rs * gv.w + bv.w;
    ((float4*)row)[tid] = o;
}

extern "C" void kernel_launch(void* const* d_in, const int* in_sizes, int n_in,
                              void* d_out, int out_size, void* d_ws, size_t ws_size,
                              hipStream_t stream) {
    const float* x   = (const float*)d_in[0];
    const float* rw  = (const float*)d_in[1];
    const float* wfc = (const float*)d_in[2];
    const float* bfc = (const float*)d_in[3];
    const float* wpr = (const float*)d_in[4];
    const float* bpr = (const float*)d_in[5];
    const float* lng = (const float*)d_in[6];
    const float* lnb = (const float*)d_in[7];

    float* out = (float*)d_out;                       // [16384,1024]
    float* logits = out + (size_t)NTOK * DDIM;        // [16384,8]

    char* ws = (char*)d_ws;
    unsigned short* xb     = (unsigned short*)(ws + WS_XB);
    unsigned short* wfcb   = (unsigned short*)(ws + WS_WFCB);
    unsigned short* wprojb = (unsigned short*)(ws + WS_WPROJB);
    unsigned short* hbuf   = (unsigned short*)(ws + WS_H);

    // Pick the largest chunk size (h tiles) that fits in ws. ws_size is fixed
    // across calls, so this branch is graph-capture safe.
    size_t aux_bytes = (size_t)PADPAIRS * 8 + (size_t)NTOK * 16 + 4096;
    int ct = 66;                                      // fallback (4 chunks, known-fit)
    if (ws_size >= WS_H + (size_t)264 * 128 * FDIM * 2 + aux_bytes)      ct = 264;
    else if (ws_size >= WS_H + (size_t)132 * 128 * FDIM * 2 + aux_bytes) ct = 132;
    int nchunks = MAXTILES / ct;

    char* aux = ws + WS_H + (size_t)ct * 128 * FDIM * 2;
    int*   ptok  = (int*)aux;
    float* pgate = (float*)(aux + (size_t)PADPAIRS * 4);
    int*   tidx  = (int*)(aux + (size_t)PADPAIRS * 8);
    float* tgate = (float*)(aux + (size_t)PADPAIRS * 8 + (size_t)NTOK * 8);
    int*   meta  = (int*)(aux + (size_t)PADPAIRS * 8 + (size_t)NTOK * 16);
    int* counts = meta;          // 8
    int* cursor = meta + 8;      // 8
    int* segs   = meta + 16;     // 8
    int* total  = meta + 24;     // 1
    int* tile2e = meta + 32;     // 264

    hipMemsetAsync(out, 0, (size_t)NTOK * DDIM * sizeof(float), stream);
    hipMemsetAsync(meta, 0, 64, stream);

    convert_kernel<<<(NEXP * FDIM * DDIM) / 4 / 256, 256, 0, stream>>>(wfc, wfcb);
    convert_kernel<<<(NEXP * DDIM * FDIM) / 4 / 256, 256, 0, stream>>>(wpr, wprojb);
    router_kernel<<<NTOK / 16, 256, 0, stream>>>(x, rw, xb, logits, tidx, tgate, counts);
    seg_plan<<<1, 256, 0, stream>>>(counts, segs, tile2e, total, ptok, pgate);
    scatter_k<<<NTOK / 256, 256, 0, stream>>>(tidx, tgate, segs, cursor, ptok, pgate);

    for (int c = 0; c < nchunks; c++) {
        gemm1_kernel<<<dim3(FDIM / 128, ct), 256, 0, stream>>>(
            xb, wfcb, bfc, ptok, tile2e, c * ct, hbuf);
        gemm2_kernel<<<dim3(DDIM / 128, ct), 256, 0, stream>>>(
            hbuf, wprojb, bpr, ptok, pgate, tile2e, c * ct, out);
    }
    ln_kernel<<<NTOK, 256, 0, stream>>>(out, lng, lnb);
}